// Round 2
// 216.195 us; speedup vs baseline: 1.0203x; 1.0203x over previous
//
#include <hip/hip_runtime.h>

#define BB 256
#define TT 256
#define CC 512
#define HH 64

typedef __bf16 bf16;
typedef __bf16 bf16x4 __attribute__((ext_vector_type(4)));
typedef __bf16 bf16x8 __attribute__((ext_vector_type(8)));
typedef float  f32x4  __attribute__((ext_vector_type(4)));

#define MFMA16(a, b, c) __builtin_amdgcn_mfma_f32_16x16x32_bf16((a), (b), (c), 0, 0, 0)

typedef __attribute__((address_space(1))) const void cas1_void;
typedef __attribute__((address_space(3))) void as3_void;
// Fire-and-forget global->LDS DMA, 16 B/lane. LDS dest = wave-uniform base + lane*16.
__device__ __forceinline__ void g2lds16(const void* g, void* l) {
    __builtin_amdgcn_global_load_lds((cas1_void*)g, (as3_void*)l, 16, 0, 0);
}

// ---------------------------------------------------------------------------
// K0: transpose fp32 weights into bf16 wt[which][n][k]. 4 k's per thread ->
// coalesced reads (consecutive n), packed 8B writes.
// ---------------------------------------------------------------------------
__global__ __launch_bounds__(256) void wtrans(const float* __restrict__ Wk,
                                              const float* __restrict__ Wq,
                                              const float* __restrict__ Wv,
                                              bf16* __restrict__ wt) {
    int which = blockIdx.y;
    const float* W = (which == 0) ? Wq : (which == 1) ? Wk : Wv;
    int idx = blockIdx.x * 256 + threadIdx.x;   // 0..8191
    int n = idx & 63, k4 = idx >> 6;            // k4: 0..127
    bf16x4 o;
    #pragma unroll
    for (int i = 0; i < 4; ++i) o[i] = (bf16)W[(k4 * 4 + i) * HH + n];
    *(bf16x4*)(&wt[which * (CC * HH) + n * CC + k4 * 4]) = o;
}

// ---------------------------------------------------------------------------
// K1: fused QKV GEMM. 512 blocks x 256 thr; M-tile 128, BK=64.
// BOTH operands DMA-staged into swizzled LDS each kc:
//   x (fp32, 32 KB, 8 insts)  unit u of row r at slot u^(r&15)
//   wt (bf16, 24 KB, 6 insts/wave) unit u of row n at slot u^(n&7)
// No register-landing global loads in the K-loop -> no 16-segment splinter
// traffic, wt bytes cut 4x (LDS shared across the block's 4 waves).
// ---------------------------------------------------------------------------
__global__ __launch_bounds__(256, 2) void qkv_gemm(const float* __restrict__ x,
                                                   const bf16* __restrict__ wt,
                                                   bf16* __restrict__ q,
                                                   bf16* __restrict__ k,
                                                   bf16* __restrict__ vt) {
    __shared__ float xs[128 * 64];      // 32 KB
    __shared__ bf16  wts[192 * 64];     // 24 KB; row n = 8 x 16B units, swizzled
    const int tid  = threadIdx.x;
    const int wv   = tid >> 6;
    const int lane = tid & 63;
    const int quad = lane >> 4;
    const int l15  = lane & 15;
    const int l7   = l15 & 7;
    const int rows0 = blockIdx.x * 128;

    f32x4 acc[2][12];
    #pragma unroll
    for (int mt = 0; mt < 2; ++mt)
        #pragma unroll
        for (int nt = 0; nt < 12; ++nt)
            acc[mt][nt] = (f32x4){0.f, 0.f, 0.f, 0.f};

    for (int kc = 0; kc < 8; ++kc) {
        __syncthreads();                // prev-iter LDS readers done
        // stage x[rows0..+128][kc*64..+64] -> xs (2048 16B-slots, 8 insts)
        #pragma unroll
        for (int j = 0; j < 8; ++j) {
            int s = j * 256 + tid;      // slot
            int r = s >> 4, up = s & 15;
            int u = up ^ (r & 15);      // global 16B-unit for this slot
            const float* gp = x + (size_t)(rows0 + r) * CC + kc * 64 + u * 4;
            g2lds16(gp, (char*)xs + (j * 256 + wv * 64) * 16);
        }
        // stage wt[0..192][kc*64..+64] -> wts (6 insts per wave, 8 n-rows each)
        #pragma unroll
        for (int j = 0; j < 6; ++j) {
            int n0 = wv * 48 + j * 8;
            int n  = n0 + (lane >> 3);
            int u  = (lane & 7) ^ (n & 7);
            const bf16* gp = wt + (size_t)n * CC + kc * 64 + u * 8;
            g2lds16(gp, (char*)wts + n0 * 128);
        }
        __syncthreads();                // drains vmcnt(0): both tiles staged

        #pragma unroll
        for (int mt = 0; mt < 2; ++mt) {
            int row = wv * 32 + mt * 16 + l15;
            const char* rp = (const char*)xs + row * 256;
            f32x4 x0 = *(const f32x4*)(rp + (((quad * 2)     ^ l15) * 16));
            f32x4 x1 = *(const f32x4*)(rp + (((quad * 2 + 1) ^ l15) * 16));
            f32x4 x2 = *(const f32x4*)(rp + (((8 + quad * 2)     ^ l15) * 16));
            f32x4 x3 = *(const f32x4*)(rp + (((8 + quad * 2 + 1) ^ l15) * 16));
            bf16x8 a0, a1;
            #pragma unroll
            for (int j = 0; j < 4; ++j) {
                a0[j] = (bf16)x0[j]; a0[j + 4] = (bf16)x1[j];
                a1[j] = (bf16)x2[j]; a1[j + 4] = (bf16)x3[j];
            }
            #pragma unroll
            for (int nt = 0; nt < 12; ++nt) {
                int n = (nt >> 2) * 64 + (nt & 3) * 16 + l15;   // n&7 == l7
                const char* np = (const char*)wts + n * 128;
                bf16x8 b0 = *(const bf16x8*)(np + ((quad ^ l7) * 16));
                bf16x8 b1 = *(const bf16x8*)(np + (((4 + quad) ^ l7) * 16));
                acc[mt][nt] = MFMA16(a0, b0, acc[mt][nt]);
                acc[mt][nt] = MFMA16(a1, b1, acc[mt][nt]);
            }
        }
    }

    const float scale = 0.044194173824159216f;  // 512^-0.5, folded into q
    #pragma unroll
    for (int mt = 0; mt < 2; ++mt) {
        int gt = rows0 + wv * 32 + mt * 16 + quad * 4;   // + r
        #pragma unroll
        for (int nt = 0; nt < 12; ++nt) {
            int h = (nt & 3) * 16 + l15;
            int wch = nt >> 2;
            if (wch == 0) {
                #pragma unroll
                for (int r = 0; r < 4; ++r)
                    q[(gt + r) * HH + h] = (bf16)(acc[mt][nt][r] * scale);
            } else if (wch == 1) {
                #pragma unroll
                for (int r = 0; r < 4; ++r)
                    k[(gt + r) * HH + h] = (bf16)(acc[mt][nt][r]);
            } else {
                int bb = gt >> 8;
                int tloc = gt & 255;
                bf16x4 pv;
                #pragma unroll
                for (int r = 0; r < 4; ++r) pv[r] = (bf16)(acc[mt][nt][r]);
                *(bf16x4*)(&vt[(bb * HH + h) * TT + tloc]) = pv;
            }
        }
    }
}

// ---------------------------------------------------------------------------
// K2: causal attention, one block per batch (grid 256 x 512 thr, 1 block/CU).
// 8 waves (2 waves/SIMD) for latency hiding. Q is not LDS-staged (each q row
// read exactly once -> staging was pure overhead); B-frags load straight from
// global (L2-hot). K,V^T DMA-staged into XOR-swizzled LDS once (64 KB, one
// barrier). Wave wv owns row-tiles {wv, 15-wv} (17 QK ct-iters + 9 PV iters
// per wave -- exactly balanced). Transposed-S formulation, softmax stats via
// 2 shuffles, P^T via per-wave pbuf LDS.
// ---------------------------------------------------------------------------
__global__ __launch_bounds__(512) void attn(const bf16* __restrict__ q,
                                            const bf16* __restrict__ k,
                                            const bf16* __restrict__ vt,
                                            float* __restrict__ out) {
    __shared__ bf16 ks[256 * 64];       // 32 KB, unit u of row r at u^(r&7)
    __shared__ bf16 vs[64 * 256];       // 32 KB, unit u of row r at u^(r&31)
    __shared__ bf16 pbuf[8][16 * 264];  // 66 KB, per-wave P^T
    const int tid  = threadIdx.x;
    const int wv   = tid >> 6;          // 0..7
    const int lane = tid & 63;
    const int quad = lane >> 4;
    const int l15  = lane & 15;
    const int b    = blockIdx.x;

    // ---- stage k (8 units/row) and vt (32 units/row): 8 insts/wave ----
    #pragma unroll
    for (int j = 0; j < 4; ++j) {
        int c = wv * 4 + j;             // chunk 0..31 (64 slots each)
        int s = c * 64 + lane;
        {   // ks
            int r = s >> 3, up = s & 7, u = up ^ (r & 7);
            const bf16* gk = k + ((size_t)b * TT + r) * HH + u * 8;
            g2lds16(gk, (char*)ks + c * 1024);
        }
        {   // vs
            int r = s >> 5, up = s & 31, u = up ^ (r & 31);
            const bf16* gv = vt + ((size_t)b * HH + r) * TT + u * 8;
            g2lds16(gv, (char*)vs + c * 1024);
        }
    }
    __syncthreads();                    // drains all DMA

    bf16* pb = &pbuf[wv][0];
    const int l7 = l15 & 7;

    #pragma unroll
    for (int ti = 0; ti < 2; ++ti) {
        const int rt = (ti == 0) ? wv : (15 - wv);
        const int rowbase = rt * 16;
        const int ctmax = rt;

        // Q B-frags straight from global: row rowbase+l15, h = quad*8 (+32)
        const bf16* qrow = q + ((size_t)b * TT + rowbase + l15) * HH;
        bf16x8 bq0 = *(const bf16x8*)(qrow + quad * 8);
        bf16x8 bq1 = *(const bf16x8*)(qrow + 32 + quad * 8);

        // Phase 1: S^T tiles
        f32x4 sv[16];
        #pragma unroll
        for (int ct = 0; ct < 16; ++ct) {
            if (ct <= ctmax) {          // wave-uniform
                const char* kp = (const char*)ks + (ct * 16 + l15) * 128;
                bf16x8 k0 = *(const bf16x8*)(kp + ((quad ^ l7) * 16));
                bf16x8 k1 = *(const bf16x8*)(kp + (((4 + quad) ^ l7) * 16));
                f32x4 a = (f32x4){0.f, 0.f, 0.f, 0.f};
                a = MFMA16(k0, bq0, a);
                a = MFMA16(k1, bq1, a);
                int t = rowbase + l15;
                #pragma unroll
                for (int r = 0; r < 4; ++r) {
                    int s = ct * 16 + quad * 4 + r;
                    sv[ct][r] = (s <= t) ? a[r] : -3.0e38f;
                }
            }
        }

        // Phase 2: row max
        float mx = -3.0e38f;
        #pragma unroll
        for (int ct = 0; ct < 16; ++ct)
            if (ct <= ctmax) {
                #pragma unroll
                for (int r = 0; r < 4; ++r) mx = fmaxf(mx, sv[ct][r]);
            }
        mx = fmaxf(mx, __shfl_xor(mx, 16));
        mx = fmaxf(mx, __shfl_xor(mx, 32));

        // Phase 3: exp + batched P^T writes
        float sm = 0.f;
        #pragma unroll
        for (int ct = 0; ct < 16; ++ct) {
            if (ct <= ctmax) {
                bf16x4 ev;
                #pragma unroll
                for (int r = 0; r < 4; ++r) {
                    float e = __expf(sv[ct][r] - mx);
                    sm += e;
                    ev[r] = (bf16)e;
                }
                *(bf16x4*)(&pb[l15 * 264 + ct * 16 + quad * 4]) = ev;
            }
        }
        if (!(ctmax & 1)) {             // zero dead half of last 32-chunk
            int ctz = ctmax + 1;
            *(bf16x4*)(&pb[l15 * 264 + ctz * 16 + quad * 4]) =
                (bf16x4){(bf16)0.f, (bf16)0.f, (bf16)0.f, (bf16)0.f};
        }
        sm += __shfl_xor(sm, 16);
        sm += __shfl_xor(sm, 32);
        asm volatile("" ::: "memory");  // keep ds_reads after ds_writes

        // Phase 4: PV from LDS
        f32x4 o[4];
        #pragma unroll
        for (int ht = 0; ht < 4; ++ht) o[ht] = (f32x4){0.f, 0.f, 0.f, 0.f};
        #pragma unroll
        for (int ks2 = 0; ks2 < 8; ++ks2) {
            if (ks2 <= (ctmax >> 1)) {  // wave-uniform
                bf16x8 pf = *(const bf16x8*)(&pb[l15 * 264 + ks2 * 32 + quad * 8]);
                #pragma unroll
                for (int ht = 0; ht < 4; ++ht) {
                    int vr = ht * 16 + l15;
                    bf16x8 vf = *(const bf16x8*)((const char*)vs + vr * 512
                                                 + (((ks2 * 4 + quad) ^ (vr & 31)) * 16));
                    o[ht] = MFMA16(vf, pf, o[ht]);
                }
            }
        }

        // Epilogue: normalize + packed fp32 stores (O^T: col=l15=qrow)
        float rinv = 1.0f / sm;
        int t = rowbase + l15;
        #pragma unroll
        for (int ht = 0; ht < 4; ++ht) {
            f32x4 ov;
            #pragma unroll
            for (int r = 0; r < 4; ++r) ov[r] = o[ht][r] * rinv;
            *(f32x4*)(&out[((size_t)b * TT + t) * HH + ht * 16 + quad * 4]) = ov;
        }
        asm volatile("" ::: "memory");  // pbuf reuse next tile: keep order
    }
}

// ---------------------------------------------------------------------------
extern "C" void kernel_launch(void* const* d_in, const int* in_sizes, int n_in,
                              void* d_out, int out_size, void* d_ws, size_t ws_size,
                              hipStream_t stream) {
    const float* x  = (const float*)d_in[0];
    const float* Wk = (const float*)d_in[1];
    const float* Wq = (const float*)d_in[2];
    const float* Wv = (const float*)d_in[3];

    bf16* ws = (bf16*)d_ws;
    bf16* wt = ws;                                   // 3 * 512*64 elems
    bf16* q  = ws + 3 * CC * HH;
    bf16* k  = q + (size_t)BB * TT * HH;
    bf16* vt = k + (size_t)BB * TT * HH;
    float* out = (float*)d_out;

    wtrans<<<dim3(32, 3), 256, 0, stream>>>(Wk, Wq, Wv, wt);
    qkv_gemm<<<dim3(512), 256, 0, stream>>>(x, wt, q, k, vt);
    attn<<<dim3(256), 512, 0, stream>>>(q, k, vt, out);
}

// Round 3
// 214.759 us; speedup vs baseline: 1.0271x; 1.0067x over previous
//
#include <hip/hip_runtime.h>

#define BB 256
#define TT 256
#define CC 512
#define HH 64

typedef __bf16 bf16;
typedef __bf16 bf16x4 __attribute__((ext_vector_type(4)));
typedef __bf16 bf16x8 __attribute__((ext_vector_type(8)));
typedef float  f32x4  __attribute__((ext_vector_type(4)));

#define MFMA16(a, b, c) __builtin_amdgcn_mfma_f32_16x16x32_bf16((a), (b), (c), 0, 0, 0)

typedef __attribute__((address_space(1))) const void cas1_void;
typedef __attribute__((address_space(3))) void as3_void;
// Fire-and-forget global->LDS DMA, 16 B/lane. LDS dest = wave-uniform base + lane*16.
__device__ __forceinline__ void g2lds16(const void* g, void* l) {
    __builtin_amdgcn_global_load_lds((cas1_void*)g, (as3_void*)l, 16, 0, 0);
}

// ---------------------------------------------------------------------------
// K0: transpose fp32 weights into bf16 wt[which][n][k]. 4 k's per thread ->
// coalesced reads (consecutive n), packed 8B writes.
// ---------------------------------------------------------------------------
__global__ __launch_bounds__(256) void wtrans(const float* __restrict__ Wk,
                                              const float* __restrict__ Wq,
                                              const float* __restrict__ Wv,
                                              bf16* __restrict__ wt) {
    int which = blockIdx.y;
    const float* W = (which == 0) ? Wq : (which == 1) ? Wk : Wv;
    int idx = blockIdx.x * 256 + threadIdx.x;   // 0..8191
    int n = idx & 63, k4 = idx >> 6;            // k4: 0..127
    bf16x4 o;
    #pragma unroll
    for (int i = 0; i < 4; ++i) o[i] = (bf16)W[(k4 * 4 + i) * HH + n];
    *(bf16x4*)(&wt[which * (CC * HH) + n * CC + k4 * 4]) = o;
}

// ---------------------------------------------------------------------------
// K1: fused QKV GEMM. 512 blocks x 256 thr; M-tile 128, NOW BK=32 with
// double-buffered LDS (T3 2-phase): stage kc+1 is issued BEFORE compute of
// kc, so HBM loads fly under the ds_read/MFMA phase instead of the CU
// idling at a vmcnt(0) drain. LDS stays 56 KB total (2 x 28 KB buffers)
// -> still 2 blocks/CU for cross-block overlap on top.
//   x buf: 128 rows x 32 f32, row = 8 x 16B units, slot u of row r at u^(r&7)
//   wt buf: 192 rows x 32 bf16, row = 4 x 16B units, slot u of row n at u^(n&3)
// ---------------------------------------------------------------------------
__global__ __launch_bounds__(256, 2) void qkv_gemm(const float* __restrict__ x,
                                                   const bf16* __restrict__ wt,
                                                   bf16* __restrict__ q,
                                                   bf16* __restrict__ k,
                                                   bf16* __restrict__ vt) {
    __shared__ float xs[2][128 * 32];   // 2 x 16 KB
    __shared__ bf16  wts[2][192 * 32];  // 2 x 12 KB
    const int tid  = threadIdx.x;
    const int wv   = tid >> 6;
    const int lane = tid & 63;
    const int quad = lane >> 4;
    const int l15  = lane & 15;
    const int l7   = l15 & 7;
    const int l3   = l15 & 3;
    const int rows0 = blockIdx.x * 128;

    // stage one BK=32 K-slab into buffer p (7 DMA insts/wave)
    auto stage = [&](int p, int kc) {
        // x[rows0..+128][kc*32..+32] -> xs[p]: 1024 16B-slots
        #pragma unroll
        for (int j = 0; j < 4; ++j) {
            int s = j * 256 + tid;          // slot
            int r = s >> 3, up = s & 7;
            int u = up ^ (r & 7);           // global 16B-unit for this slot
            const float* gp = x + (size_t)(rows0 + r) * CC + kc * 32 + u * 4;
            g2lds16(gp, (char*)&xs[p][0] + (j * 256 + wv * 64) * 16);
        }
        // wt[0..192][kc*32..+32] -> wts[p]: 768 16B-slots (3 insts/wave)
        #pragma unroll
        for (int j = 0; j < 3; ++j) {
            int n0 = wv * 48 + j * 16;
            int n  = n0 + (lane >> 2);
            int u  = (lane & 3) ^ (n & 3);
            const bf16* gp = wt + (size_t)n * CC + kc * 32 + u * 8;
            g2lds16(gp, (char*)&wts[p][0] + n0 * 64);
        }
    };

    f32x4 acc[2][12];
    #pragma unroll
    for (int mt = 0; mt < 2; ++mt)
        #pragma unroll
        for (int nt = 0; nt < 12; ++nt)
            acc[mt][nt] = (f32x4){0.f, 0.f, 0.f, 0.f};

    stage(0, 0);
    __syncthreads();                        // drains prologue DMA

    for (int kc = 0; kc < 16; ++kc) {
        int p = kc & 1;
        if (kc < 15) stage(p ^ 1, kc + 1);  // prefetch flies under compute

        const char* xbase = (const char*)&xs[p][0];
        const char* wbase = (const char*)&wts[p][0];
        #pragma unroll
        for (int mt = 0; mt < 2; ++mt) {
            int row = wv * 32 + mt * 16 + l15;
            const char* rp = xbase + row * 128;
            f32x4 x0 = *(const f32x4*)(rp + (((quad * 2)     ^ l7) * 16));
            f32x4 x1 = *(const f32x4*)(rp + (((quad * 2 + 1) ^ l7) * 16));
            bf16x8 a0;
            #pragma unroll
            for (int j = 0; j < 4; ++j) {
                a0[j] = (bf16)x0[j]; a0[j + 4] = (bf16)x1[j];
            }
            #pragma unroll
            for (int nt = 0; nt < 12; ++nt) {
                int n = (nt >> 2) * 64 + (nt & 3) * 16 + l15;   // n&3 == l3
                const char* np = wbase + n * 64;
                bf16x8 b0 = *(const bf16x8*)(np + ((quad ^ l3) * 16));
                acc[mt][nt] = MFMA16(a0, b0, acc[mt][nt]);
            }
        }
        if (kc < 15) __syncthreads();       // readers done + prefetch drained
    }

    const float scale = 0.044194173824159216f;  // 512^-0.5, folded into q
    #pragma unroll
    for (int mt = 0; mt < 2; ++mt) {
        int gt = rows0 + wv * 32 + mt * 16 + quad * 4;   // + r
        #pragma unroll
        for (int nt = 0; nt < 12; ++nt) {
            int h = (nt & 3) * 16 + l15;
            int wch = nt >> 2;
            if (wch == 0) {
                #pragma unroll
                for (int r = 0; r < 4; ++r)
                    q[(gt + r) * HH + h] = (bf16)(acc[mt][nt][r] * scale);
            } else if (wch == 1) {
                #pragma unroll
                for (int r = 0; r < 4; ++r)
                    k[(gt + r) * HH + h] = (bf16)(acc[mt][nt][r]);
            } else {
                int bb = gt >> 8;
                int tloc = gt & 255;
                bf16x4 pv;
                #pragma unroll
                for (int r = 0; r < 4; ++r) pv[r] = (bf16)(acc[mt][nt][r]);
                *(bf16x4*)(&vt[(bb * HH + h) * TT + tloc]) = pv;
            }
        }
    }
}

// ---------------------------------------------------------------------------
// K2: causal attention, one block per batch (grid 256 x 512 thr, 1 block/CU).
// 8 waves (2 waves/SIMD) for latency hiding. Q is not LDS-staged (each q row
// read exactly once -> staging was pure overhead); B-frags load straight from
// global (L2-hot). K,V^T DMA-staged into XOR-swizzled LDS once (64 KB, one
// barrier). Wave wv owns row-tiles {wv, 15-wv} (17 QK ct-iters + 9 PV iters
// per wave -- exactly balanced). Transposed-S formulation, softmax stats via
// 2 shuffles, P^T via per-wave pbuf LDS.
// ---------------------------------------------------------------------------
__global__ __launch_bounds__(512) void attn(const bf16* __restrict__ q,
                                            const bf16* __restrict__ k,
                                            const bf16* __restrict__ vt,
                                            float* __restrict__ out) {
    __shared__ bf16 ks[256 * 64];       // 32 KB, unit u of row r at u^(r&7)
    __shared__ bf16 vs[64 * 256];       // 32 KB, unit u of row r at u^(r&31)
    __shared__ bf16 pbuf[8][16 * 264];  // 66 KB, per-wave P^T
    const int tid  = threadIdx.x;
    const int wv   = tid >> 6;          // 0..7
    const int lane = tid & 63;
    const int quad = lane >> 4;
    const int l15  = lane & 15;
    const int b    = blockIdx.x;

    // ---- stage k (8 units/row) and vt (32 units/row): 8 insts/wave ----
    #pragma unroll
    for (int j = 0; j < 4; ++j) {
        int c = wv * 4 + j;             // chunk 0..31 (64 slots each)
        int s = c * 64 + lane;
        {   // ks
            int r = s >> 3, up = s & 7, u = up ^ (r & 7);
            const bf16* gk = k + ((size_t)b * TT + r) * HH + u * 8;
            g2lds16(gk, (char*)ks + c * 1024);
        }
        {   // vs
            int r = s >> 5, up = s & 31, u = up ^ (r & 31);
            const bf16* gv = vt + ((size_t)b * HH + r) * TT + u * 8;
            g2lds16(gv, (char*)vs + c * 1024);
        }
    }
    __syncthreads();                    // drains all DMA

    bf16* pb = &pbuf[wv][0];
    const int l7 = l15 & 7;

    #pragma unroll
    for (int ti = 0; ti < 2; ++ti) {
        const int rt = (ti == 0) ? wv : (15 - wv);
        const int rowbase = rt * 16;
        const int ctmax = rt;

        // Q B-frags straight from global: row rowbase+l15, h = quad*8 (+32)
        const bf16* qrow = q + ((size_t)b * TT + rowbase + l15) * HH;
        bf16x8 bq0 = *(const bf16x8*)(qrow + quad * 8);
        bf16x8 bq1 = *(const bf16x8*)(qrow + 32 + quad * 8);

        // Phase 1: S^T tiles
        f32x4 sv[16];
        #pragma unroll
        for (int ct = 0; ct < 16; ++ct) {
            if (ct <= ctmax) {          // wave-uniform
                const char* kp = (const char*)ks + (ct * 16 + l15) * 128;
                bf16x8 k0 = *(const bf16x8*)(kp + ((quad ^ l7) * 16));
                bf16x8 k1 = *(const bf16x8*)(kp + (((4 + quad) ^ l7) * 16));
                f32x4 a = (f32x4){0.f, 0.f, 0.f, 0.f};
                a = MFMA16(k0, bq0, a);
                a = MFMA16(k1, bq1, a);
                int t = rowbase + l15;
                #pragma unroll
                for (int r = 0; r < 4; ++r) {
                    int s = ct * 16 + quad * 4 + r;
                    sv[ct][r] = (s <= t) ? a[r] : -3.0e38f;
                }
            }
        }

        // Phase 2: row max
        float mx = -3.0e38f;
        #pragma unroll
        for (int ct = 0; ct < 16; ++ct)
            if (ct <= ctmax) {
                #pragma unroll
                for (int r = 0; r < 4; ++r) mx = fmaxf(mx, sv[ct][r]);
            }
        mx = fmaxf(mx, __shfl_xor(mx, 16));
        mx = fmaxf(mx, __shfl_xor(mx, 32));

        // Phase 3: exp + batched P^T writes
        float sm = 0.f;
        #pragma unroll
        for (int ct = 0; ct < 16; ++ct) {
            if (ct <= ctmax) {
                bf16x4 ev;
                #pragma unroll
                for (int r = 0; r < 4; ++r) {
                    float e = __expf(sv[ct][r] - mx);
                    sm += e;
                    ev[r] = (bf16)e;
                }
                *(bf16x4*)(&pb[l15 * 264 + ct * 16 + quad * 4]) = ev;
            }
        }
        if (!(ctmax & 1)) {             // zero dead half of last 32-chunk
            int ctz = ctmax + 1;
            *(bf16x4*)(&pb[l15 * 264 + ctz * 16 + quad * 4]) =
                (bf16x4){(bf16)0.f, (bf16)0.f, (bf16)0.f, (bf16)0.f};
        }
        sm += __shfl_xor(sm, 16);
        sm += __shfl_xor(sm, 32);
        asm volatile("" ::: "memory");  // keep ds_reads after ds_writes

        // Phase 4: PV from LDS
        f32x4 o[4];
        #pragma unroll
        for (int ht = 0; ht < 4; ++ht) o[ht] = (f32x4){0.f, 0.f, 0.f, 0.f};
        #pragma unroll
        for (int ks2 = 0; ks2 < 8; ++ks2) {
            if (ks2 <= (ctmax >> 1)) {  // wave-uniform
                bf16x8 pf = *(const bf16x8*)(&pb[l15 * 264 + ks2 * 32 + quad * 8]);
                #pragma unroll
                for (int ht = 0; ht < 4; ++ht) {
                    int vr = ht * 16 + l15;
                    bf16x8 vf = *(const bf16x8*)((const char*)vs + vr * 512
                                                 + (((ks2 * 4 + quad) ^ (vr & 31)) * 16));
                    o[ht] = MFMA16(vf, pf, o[ht]);
                }
            }
        }

        // Epilogue: normalize + packed fp32 stores (O^T: col=l15=qrow)
        float rinv = 1.0f / sm;
        int t = rowbase + l15;
        #pragma unroll
        for (int ht = 0; ht < 4; ++ht) {
            f32x4 ov;
            #pragma unroll
            for (int r = 0; r < 4; ++r) ov[r] = o[ht][r] * rinv;
            *(f32x4*)(&out[((size_t)b * TT + t) * HH + ht * 16 + quad * 4]) = ov;
        }
        asm volatile("" ::: "memory");  // pbuf reuse next tile: keep order
    }
}

// ---------------------------------------------------------------------------
extern "C" void kernel_launch(void* const* d_in, const int* in_sizes, int n_in,
                              void* d_out, int out_size, void* d_ws, size_t ws_size,
                              hipStream_t stream) {
    const float* x  = (const float*)d_in[0];
    const float* Wk = (const float*)d_in[1];
    const float* Wq = (const float*)d_in[2];
    const float* Wv = (const float*)d_in[3];

    bf16* ws = (bf16*)d_ws;
    bf16* wt = ws;                                   // 3 * 512*64 elems
    bf16* q  = ws + 3 * CC * HH;
    bf16* k  = q + (size_t)BB * TT * HH;
    bf16* vt = k + (size_t)BB * TT * HH;
    float* out = (float*)d_out;

    wtrans<<<dim3(32, 3), 256, 0, stream>>>(Wk, Wq, Wv, wt);
    qkv_gemm<<<dim3(512), 256, 0, stream>>>(x, wt, q, k, vt);
    attn<<<dim3(256), 512, 0, stream>>>(q, k, vt, out);
}

// Round 4
// 210.850 us; speedup vs baseline: 1.0461x; 1.0185x over previous
//
#include <hip/hip_runtime.h>

#define BB 256
#define TT 256
#define CC 512
#define HH 64

typedef __bf16 bf16;
typedef __bf16 bf16x4 __attribute__((ext_vector_type(4)));
typedef __bf16 bf16x8 __attribute__((ext_vector_type(8)));
typedef float  f32x4  __attribute__((ext_vector_type(4)));

#define MFMA16(a, b, c) __builtin_amdgcn_mfma_f32_16x16x32_bf16((a), (b), (c), 0, 0, 0)

typedef __attribute__((address_space(1))) const void cas1_void;
typedef __attribute__((address_space(3))) void as3_void;
// Fire-and-forget global->LDS DMA, 16 B/lane. LDS dest = wave-uniform base + lane*16.
__device__ __forceinline__ void g2lds16(const void* g, void* l) {
    __builtin_amdgcn_global_load_lds((cas1_void*)g, (as3_void*)l, 16, 0, 0);
}

// ---------------------------------------------------------------------------
// K0: transpose fp32 weights into bf16 wt[n][k] (n = 0..191 spanning q,k,v).
// ---------------------------------------------------------------------------
__global__ __launch_bounds__(256) void wtrans(const float* __restrict__ Wk,
                                              const float* __restrict__ Wq,
                                              const float* __restrict__ Wv,
                                              bf16* __restrict__ wt) {
    int which = blockIdx.y;
    const float* W = (which == 0) ? Wq : (which == 1) ? Wk : Wv;
    int idx = blockIdx.x * 256 + threadIdx.x;   // 0..8191
    int n = idx & 63, k4 = idx >> 6;            // k4: 0..127
    bf16x4 o;
    #pragma unroll
    for (int i = 0; i < 4; ++i) o[i] = (bf16)W[(k4 * 4 + i) * HH + n];
    *(bf16x4*)(&wt[which * (CC * HH) + n * CC + k4 * 4]) = o;
}

// ---------------------------------------------------------------------------
// K1: FULLY FUSED qkv+attention. One block per batch (grid 256 x 512 thr,
// 1 block/CU, 128 KB LDS). Phase G: M=256 GEMM vs wt, BK=32 double-buffered
// DMA staging (round-3-verified inner loop, 8 waves x 32 rows). Epilogue
// writes q/k/v straight into swizzled LDS (q/k row-major u^(r&7); v^T
// [h][t] u^(h&31)) -- the 48 MiB q/k/vt HBM round-trip is gone. Phase A:
// round-3-verified attention body reading Q/K/V from LDS; P^T goes through
// a 4 KB/wave pbuf in two half-passes (exp ct 0-7 -> PV ks2 0-3, then
// ct 8-15 -> ks2 4-7; pbuf is wave-private so only in-wave ordering needed).
// LDS aliasing: G-staging (88 KB) dies at the post-loop barrier, then the
// same bytes hold qs/ks/vs (96 KB); pbuf 32 KB on top = 128 KB.
// ---------------------------------------------------------------------------
__global__ __launch_bounds__(512, 2) void fused(const float* __restrict__ x,
                                                const bf16* __restrict__ wt,
                                                float* __restrict__ out) {
    __shared__ __align__(16) char smem[131072];
    const int tid  = threadIdx.x;
    const int wv   = tid >> 6;          // 0..7
    const int lane = tid & 63;
    const int quad = lane >> 4;
    const int l15  = lane & 15;
    const int l7   = l15 & 7;
    const int l3   = l15 & 3;
    const int b    = blockIdx.x;
    const float* xg = x + (size_t)b * TT * CC;

    // ---- stage one BK=32 slab: x[256][32] (16 KB->32KB fp32) + wt[192][32] ----
    auto stage = [&](int p, int kc) {
        char* xbase = smem + p * 32768;
        #pragma unroll
        for (int j = 0; j < 4; ++j) {
            int s = j * 512 + tid;          // slot 0..2047
            int r = s >> 3, up = s & 7;
            int u = up ^ (r & 7);           // global 16B-unit for this slot
            const float* gp = xg + (size_t)r * CC + kc * 32 + u * 4;
            g2lds16(gp, xbase + (j * 512 + wv * 64) * 16);
        }
        if (wv < 6) {                       // wave-uniform: 6 waves x 32 n-rows
            char* wbase = smem + 65536 + p * 12288;
            #pragma unroll
            for (int j = 0; j < 2; ++j) {
                int n = wv * 32 + j * 16 + (lane >> 2);
                int u = (lane & 3) ^ (n & 3);
                const bf16* gp = wt + (size_t)n * CC + kc * 32 + u * 8;
                g2lds16(gp, wbase + (wv * 32 + j * 16) * 64);
            }
        }
    };

    f32x4 acc[2][12];
    #pragma unroll
    for (int mt = 0; mt < 2; ++mt)
        #pragma unroll
        for (int nt = 0; nt < 12; ++nt)
            acc[mt][nt] = (f32x4){0.f, 0.f, 0.f, 0.f};

    stage(0, 0);
    __syncthreads();                        // drains prologue DMA

    for (int kc = 0; kc < 16; ++kc) {
        int p = kc & 1;
        if (kc < 15) stage(p ^ 1, kc + 1);  // prefetch flies under compute

        const char* xbase = smem + p * 32768;
        const char* wbase = smem + 65536 + p * 12288;
        #pragma unroll
        for (int mt = 0; mt < 2; ++mt) {
            int row = wv * 32 + mt * 16 + l15;
            const char* rp = xbase + row * 128;
            f32x4 x0 = *(const f32x4*)(rp + (((quad * 2)     ^ l7) * 16));
            f32x4 x1 = *(const f32x4*)(rp + (((quad * 2 + 1) ^ l7) * 16));
            bf16x8 a0;
            #pragma unroll
            for (int j = 0; j < 4; ++j) {
                a0[j] = (bf16)x0[j]; a0[j + 4] = (bf16)x1[j];
            }
            #pragma unroll
            for (int nt = 0; nt < 12; ++nt) {
                int n = (nt >> 2) * 64 + (nt & 3) * 16 + l15;   // n&3 == l3
                const char* np = wbase + n * 64;
                bf16x8 b0 = *(const bf16x8*)(np + ((quad ^ l3) * 16));
                acc[mt][nt] = MFMA16(a0, b0, acc[mt][nt]);
            }
        }
        __syncthreads();    // readers done + prefetch drained (also pre-epilogue)
    }

    // ---- epilogue: q/k/v accs -> swizzled LDS (staging bytes now dead) ----
    bf16* qs = (bf16*)smem;                 // [256 rows][64 h], u^(r&7)
    bf16* ks = (bf16*)(smem + 32768);       // same layout
    bf16* vs = (bf16*)(smem + 65536);       // v^T [64 h][256 t], u^(h&31)
    const float scale = 0.044194173824159216f;  // 512^-0.5, folded into q
    #pragma unroll
    for (int mt = 0; mt < 2; ++mt) {
        int gt = wv * 32 + mt * 16 + quad * 4;
        #pragma unroll
        for (int nt = 0; nt < 12; ++nt) {
            int h = (nt & 3) * 16 + l15;
            int wch = nt >> 2;
            if (wch == 0) {
                #pragma unroll
                for (int r = 0; r < 4; ++r) {
                    int row = gt + r;
                    *(bf16*)((char*)qs + row * 128 + (((h >> 3) ^ (row & 7)) * 16)
                             + (h & 7) * 2) = (bf16)(acc[mt][nt][r] * scale);
                }
            } else if (wch == 1) {
                #pragma unroll
                for (int r = 0; r < 4; ++r) {
                    int row = gt + r;
                    *(bf16*)((char*)ks + row * 128 + (((h >> 3) ^ (row & 7)) * 16)
                             + (h & 7) * 2) = (bf16)(acc[mt][nt][r]);
                }
            } else {
                bf16x4 pv;
                #pragma unroll
                for (int r = 0; r < 4; ++r) pv[r] = (bf16)(acc[mt][nt][r]);
                *(bf16x4*)((char*)vs + h * 512 + (((gt >> 3) ^ (h & 31)) * 16)
                           + ((gt >> 2) & 1) * 8) = pv;
            }
        }
    }
    __syncthreads();                        // q/k/v visible to all waves

    // ---- attention: wave wv owns row-tiles {wv, 15-wv} (balanced causal) ----
    bf16* pb = (bf16*)(smem + 98304 + wv * 4096);   // [16 cols][128 k] per half

    #pragma unroll
    for (int ti = 0; ti < 2; ++ti) {
        const int rt = (ti == 0) ? wv : (15 - wv);
        const int rowbase = rt * 16;
        const int ctmax = rt;

        // Q B-frags from LDS
        const int qr = rowbase + l15;
        const char* qp = (const char*)qs + qr * 128;
        bf16x8 bq0 = *(const bf16x8*)(qp + ((quad ^ l7) * 16));
        bf16x8 bq1 = *(const bf16x8*)(qp + (((4 + quad) ^ l7) * 16));

        // Phase 1: S^T tiles
        f32x4 sv[16];
        #pragma unroll
        for (int ct = 0; ct < 16; ++ct) {
            if (ct <= ctmax) {          // wave-uniform
                const char* kp = (const char*)ks + (ct * 16 + l15) * 128;
                bf16x8 k0 = *(const bf16x8*)(kp + ((quad ^ l7) * 16));
                bf16x8 k1 = *(const bf16x8*)(kp + (((4 + quad) ^ l7) * 16));
                f32x4 a = (f32x4){0.f, 0.f, 0.f, 0.f};
                a = MFMA16(k0, bq0, a);
                a = MFMA16(k1, bq1, a);
                int t = rowbase + l15;
                #pragma unroll
                for (int r = 0; r < 4; ++r) {
                    int s = ct * 16 + quad * 4 + r;
                    sv[ct][r] = (s <= t) ? a[r] : -3.0e38f;
                }
            }
        }

        // Phase 2: row max
        float mx = -3.0e38f;
        #pragma unroll
        for (int ct = 0; ct < 16; ++ct)
            if (ct <= ctmax) {
                #pragma unroll
                for (int r = 0; r < 4; ++r) mx = fmaxf(mx, sv[ct][r]);
            }
        mx = fmaxf(mx, __shfl_xor(mx, 16));
        mx = fmaxf(mx, __shfl_xor(mx, 32));

        // Phases 3+4 in two half-passes through the 4 KB wave-private pbuf:
        // exp+write ct in [hp*8, hp*8+7] then PV ks2 in [hp*4, hp*4+3].
        float sm = 0.f;
        f32x4 o[4];
        #pragma unroll
        for (int ht = 0; ht < 4; ++ht) o[ht] = (f32x4){0.f, 0.f, 0.f, 0.f};

        #pragma unroll
        for (int hp = 0; hp < 2; ++hp) {
            if (hp * 8 <= ctmax) {      // wave-uniform
                #pragma unroll
                for (int c2 = 0; c2 < 8; ++c2) {
                    int ct = hp * 8 + c2;
                    if (ct <= ctmax) {
                        bf16x4 ev;
                        #pragma unroll
                        for (int r = 0; r < 4; ++r) {
                            float e = __expf(sv[ct][r] - mx);
                            sm += e;
                            ev[r] = (bf16)e;
                        }
                        int u = 2 * c2 + (quad >> 1);
                        *(bf16x4*)((char*)pb + l15 * 256 + ((u ^ l15) * 16)
                                   + (quad & 1) * 8) = ev;
                    }
                }
                if (ctmax >= hp * 8 && ctmax < hp * 8 + 8 && !(ctmax & 1)) {
                    int c2z = (ctmax & 7) + 1;  // zero dead half of last 32-chunk
                    int u = 2 * c2z + (quad >> 1);
                    *(bf16x4*)((char*)pb + l15 * 256 + ((u ^ l15) * 16)
                               + (quad & 1) * 8) =
                        (bf16x4){(bf16)0.f, (bf16)0.f, (bf16)0.f, (bf16)0.f};
                }
                asm volatile("" ::: "memory");  // keep ds_reads after ds_writes

                #pragma unroll
                for (int k2 = 0; k2 < 4; ++k2) {
                    int ks2 = hp * 4 + k2;
                    if (ks2 <= (ctmax >> 1)) {  // wave-uniform
                        int ur = 4 * k2 + quad;
                        bf16x8 pf = *(const bf16x8*)((char*)pb + l15 * 256
                                                     + ((ur ^ l15) * 16));
                        #pragma unroll
                        for (int ht = 0; ht < 4; ++ht) {
                            int vr = ht * 16 + l15;
                            bf16x8 vf = *(const bf16x8*)((const char*)vs + vr * 512
                                         + (((ks2 * 4 + quad) ^ (vr & 31)) * 16));
                            o[ht] = MFMA16(vf, pf, o[ht]);
                        }
                    }
                }
                asm volatile("" ::: "memory");  // pbuf reuse next half: keep order
            }
        }
        sm += __shfl_xor(sm, 16);
        sm += __shfl_xor(sm, 32);

        // Epilogue: normalize + packed fp32 stores (O^T: col=l15=qrow)
        float rinv = 1.0f / sm;
        int t = rowbase + l15;
        #pragma unroll
        for (int ht = 0; ht < 4; ++ht) {
            f32x4 ov;
            #pragma unroll
            for (int r = 0; r < 4; ++r) ov[r] = o[ht][r] * rinv;
            *(f32x4*)(&out[((size_t)b * TT + t) * HH + ht * 16 + quad * 4]) = ov;
        }
        asm volatile("" ::: "memory");  // pbuf reuse next tile: keep order
    }
}

// ---------------------------------------------------------------------------
extern "C" void kernel_launch(void* const* d_in, const int* in_sizes, int n_in,
                              void* d_out, int out_size, void* d_ws, size_t ws_size,
                              hipStream_t stream) {
    const float* x  = (const float*)d_in[0];
    const float* Wk = (const float*)d_in[1];
    const float* Wq = (const float*)d_in[2];
    const float* Wv = (const float*)d_in[3];

    bf16* wt = (bf16*)d_ws;                          // 3 * 512*64 elems
    float* out = (float*)d_out;

    wtrans<<<dim3(32, 3), 256, 0, stream>>>(Wk, Wq, Wv, wt);
    fused<<<dim3(256), 512, 0, stream>>>(x, wt, out);
}

// Round 5
// 209.497 us; speedup vs baseline: 1.0529x; 1.0065x over previous
//
#include <hip/hip_runtime.h>

#define BB 256
#define TT 256
#define CC 512
#define HH 64

typedef __bf16 bf16;
typedef __bf16 bf16x4 __attribute__((ext_vector_type(4)));
typedef __bf16 bf16x8 __attribute__((ext_vector_type(8)));
typedef float  f32x4  __attribute__((ext_vector_type(4)));

#define MFMA16(a, b, c) __builtin_amdgcn_mfma_f32_16x16x32_bf16((a), (b), (c), 0, 0, 0)

typedef __attribute__((address_space(1))) const void cas1_void;
typedef __attribute__((address_space(3))) void as3_void;
// Fire-and-forget global->LDS DMA, 16 B/lane. LDS dest = wave-uniform base + lane*16.
__device__ __forceinline__ void g2lds16(const void* g, void* l) {
    __builtin_amdgcn_global_load_lds((cas1_void*)g, (as3_void*)l, 16, 0, 0);
}

// ---------------------------------------------------------------------------
// K0: transpose fp32 weights into bf16 wt[n][k] (n = 0..191 spanning q,k,v).
// ---------------------------------------------------------------------------
__global__ __launch_bounds__(256) void wtrans(const float* __restrict__ Wk,
                                              const float* __restrict__ Wq,
                                              const float* __restrict__ Wv,
                                              bf16* __restrict__ wt) {
    int which = blockIdx.y;
    const float* W = (which == 0) ? Wq : (which == 1) ? Wk : Wv;
    int idx = blockIdx.x * 256 + threadIdx.x;   // 0..8191
    int n = idx & 63, k4 = idx >> 6;            // k4: 0..127
    bf16x4 o;
    #pragma unroll
    for (int i = 0; i < 4; ++i) o[i] = (bf16)W[(k4 * 4 + i) * HH + n];
    *(bf16x4*)(&wt[which * (CC * HH) + n * CC + k4 * 4]) = o;
}

// ---------------------------------------------------------------------------
// K1: FULLY FUSED qkv+attention, NOW 1024 thr (16 waves = 4 waves/SIMD) for
// 2x latency hiding in the LDS-latency-bound attn phase. Grid 256, 1
// block/CU, 128 KB LDS. Phase G: M=256 GEMM vs wt, BK=32 double-buffered DMA
// staging; wave owns 16 rows (acc = 48 VGPR). Epilogue writes q/k/v into
// swizzled LDS. Phase A: one 16-row tile per wave; tile<-wave bijection
// balances causal work per SIMD ({0,3,12,15},{1,2,13,14},{4,7,8,11},
// {5,6,9,10} each sum 34 ct-iters). Softmax is ONLINE over 4 quarter-passes
// (flash rescale, exact): sv[4] regs, pbuf 2 KB/wave.
// LDS map: stage x dbuf [0,64K) + wt dbuf [64K,88K) die at last barrier;
// then qs [0,32K) ks [32K,64K) vs [64K,96K); pbuf [96K,128K).
// ---------------------------------------------------------------------------
__global__ __launch_bounds__(1024) void fused(const float* __restrict__ x,
                                              const bf16* __restrict__ wt,
                                              float* __restrict__ out) {
    __shared__ __align__(16) char smem[131072];
    const int tid  = threadIdx.x;
    const int wv   = tid >> 6;          // 0..15
    const int lane = tid & 63;
    const int quad = lane >> 4;
    const int l15  = lane & 15;
    const int l7   = l15 & 7;
    const int l3   = l15 & 3;
    const int b    = blockIdx.x;
    const float* xg = x + (size_t)b * TT * CC;

    // ---- stage one BK=32 slab: x[256][32] + wt[192][32] ----
    auto stage = [&](int p, int kc) {
        char* xbase = smem + p * 32768;
        #pragma unroll
        for (int j = 0; j < 2; ++j) {
            int s = j * 1024 + tid;         // slot 0..2047
            int r = s >> 3, up = s & 7;
            int u = up ^ (r & 7);           // global 16B-unit for this slot
            const float* gp = xg + (size_t)r * CC + kc * 32 + u * 4;
            g2lds16(gp, xbase + (j * 1024 + wv * 64) * 16);
        }
        if (wv < 12) {                      // wave-uniform: 12 waves x 16 n-rows
            char* wbase = smem + 65536 + p * 12288;
            int n = wv * 16 + (lane >> 2);
            int u = (lane & 3) ^ (n & 3);
            const bf16* gp = wt + (size_t)n * CC + kc * 32 + u * 8;
            g2lds16(gp, wbase + wv * 1024);
        }
    };

    f32x4 acc[12];
    #pragma unroll
    for (int nt = 0; nt < 12; ++nt) acc[nt] = (f32x4){0.f, 0.f, 0.f, 0.f};

    stage(0, 0);
    __syncthreads();                        // drains prologue DMA

    for (int kc = 0; kc < 16; ++kc) {
        int p = kc & 1;
        if (kc < 15) stage(p ^ 1, kc + 1);  // prefetch flies under compute

        const char* xbase = smem + p * 32768;
        const char* wbase = smem + 65536 + p * 12288;
        int row = wv * 16 + l15;
        const char* rp = xbase + row * 128;
        f32x4 x0 = *(const f32x4*)(rp + (((quad * 2)     ^ l7) * 16));
        f32x4 x1 = *(const f32x4*)(rp + (((quad * 2 + 1) ^ l7) * 16));
        bf16x8 a0;
        #pragma unroll
        for (int j = 0; j < 4; ++j) {
            a0[j] = (bf16)x0[j]; a0[j + 4] = (bf16)x1[j];
        }
        #pragma unroll
        for (int nt = 0; nt < 12; ++nt) {
            int n = (nt >> 2) * 64 + (nt & 3) * 16 + l15;   // n&3 == l3
            const char* np = wbase + n * 64;
            bf16x8 b0 = *(const bf16x8*)(np + ((quad ^ l3) * 16));
            acc[nt] = MFMA16(a0, b0, acc[nt]);
        }
        __syncthreads();    // readers done + prefetch drained (also pre-epilogue)
    }

    // ---- epilogue: q/k/v accs -> swizzled LDS (staging bytes now dead) ----
    bf16* qs = (bf16*)smem;                 // [256 rows][64 h], u^(r&7)
    bf16* ks = (bf16*)(smem + 32768);       // same layout
    bf16* vs = (bf16*)(smem + 65536);       // v^T [64 h][256 t], u^(h&31)
    const float scale = 0.044194173824159216f;  // 512^-0.5, folded into q
    {
        int gt = wv * 16 + quad * 4;
        #pragma unroll
        for (int nt = 0; nt < 12; ++nt) {
            int h = (nt & 3) * 16 + l15;
            int wch = nt >> 2;
            if (wch == 0) {
                #pragma unroll
                for (int r = 0; r < 4; ++r) {
                    int row = gt + r;
                    *(bf16*)((char*)qs + row * 128 + (((h >> 3) ^ (row & 7)) * 16)
                             + (h & 7) * 2) = (bf16)(acc[nt][r] * scale);
                }
            } else if (wch == 1) {
                #pragma unroll
                for (int r = 0; r < 4; ++r) {
                    int row = gt + r;
                    *(bf16*)((char*)ks + row * 128 + (((h >> 3) ^ (row & 7)) * 16)
                             + (h & 7) * 2) = (bf16)(acc[nt][r]);
                }
            } else {
                bf16x4 pv;
                #pragma unroll
                for (int r = 0; r < 4; ++r) pv[r] = (bf16)(acc[nt][r]);
                *(bf16x4*)((char*)vs + h * 512 + (((gt >> 3) ^ (h & 31)) * 16)
                           + ((gt >> 2) & 1) * 8) = pv;
            }
        }
    }
    __syncthreads();                        // q/k/v visible to all waves

    // ---- attention: one tile per wave, SIMD-balanced bijection ----
    bf16* pb = (bf16*)(smem + 98304 + wv * 2048);   // [16 rows][64 k] quarter
    const int w0 = wv & 1, w1 = (wv >> 1) & 1, w2 = (wv >> 2) & 1, w3 = wv >> 3;
    const int rt = (w3 << 3) | ((w1 ^ w3) << 2) | (w2 << 1) | (w0 ^ w2);
    const int rowbase = rt * 16;
    const int ctmax = rt;
    const int t = rowbase + l15;

    // Q B-frags from LDS
    const char* qp = (const char*)qs + t * 128;
    bf16x8 bq0 = *(const bf16x8*)(qp + ((quad ^ l7) * 16));
    bf16x8 bq1 = *(const bf16x8*)(qp + (((4 + quad) ^ l7) * 16));

    float m_run = -3.0e38f, sm = 0.f;
    f32x4 o[4];
    #pragma unroll
    for (int ht = 0; ht < 4; ++ht) o[ht] = (f32x4){0.f, 0.f, 0.f, 0.f};

    #pragma unroll
    for (int qp4 = 0; qp4 < 4; ++qp4) {
        if (qp4 * 4 <= ctmax) {             // wave-uniform
            // QK^T for this quarter (cts qp4*4 .. +3)
            f32x4 sv[4];
            #pragma unroll
            for (int c2 = 0; c2 < 4; ++c2) {
                int ct = qp4 * 4 + c2;
                if (ct <= ctmax) {          // wave-uniform
                    const char* kp = (const char*)ks + (ct * 16 + l15) * 128;
                    bf16x8 k0 = *(const bf16x8*)(kp + ((quad ^ l7) * 16));
                    bf16x8 k1 = *(const bf16x8*)(kp + (((4 + quad) ^ l7) * 16));
                    f32x4 a = (f32x4){0.f, 0.f, 0.f, 0.f};
                    a = MFMA16(k0, bq0, a);
                    a = MFMA16(k1, bq1, a);
                    #pragma unroll
                    for (int r = 0; r < 4; ++r) {
                        int s = ct * 16 + quad * 4 + r;
                        sv[c2][r] = (s <= t) ? a[r] : -3.0e38f;
                    }
                }
            }
            // quarter max + online rescale (exact flash combine)
            float mq = -3.0e38f;
            #pragma unroll
            for (int c2 = 0; c2 < 4; ++c2)
                if (qp4 * 4 + c2 <= ctmax) {
                    #pragma unroll
                    for (int r = 0; r < 4; ++r) mq = fmaxf(mq, sv[c2][r]);
                }
            mq = fmaxf(mq, __shfl_xor(mq, 16));
            mq = fmaxf(mq, __shfl_xor(mq, 32));
            float mnew = fmaxf(m_run, mq);
            float alpha = __expf(m_run - mnew);     // first pass: exp(-inf)=0
            sm *= alpha;
            #pragma unroll
            for (int ht = 0; ht < 4; ++ht)
                #pragma unroll
                for (int r = 0; r < 4; ++r) o[ht][r] *= alpha;
            m_run = mnew;

            // exp + P^T quarter into wave-private pbuf
            #pragma unroll
            for (int c2 = 0; c2 < 4; ++c2) {
                int ct = qp4 * 4 + c2;
                if (ct <= ctmax) {
                    bf16x4 ev;
                    #pragma unroll
                    for (int r = 0; r < 4; ++r) {
                        float e = __expf(sv[c2][r] - m_run);
                        sm += e;
                        ev[r] = (bf16)e;
                    }
                    int u = 2 * c2 + (quad >> 1);
                    *(bf16x4*)((char*)pb + l15 * 128 + ((u ^ l7) * 16)
                               + (quad & 1) * 8) = ev;
                }
            }
            if (ctmax >= qp4 * 4 && ctmax < qp4 * 4 + 4 && !(ctmax & 1)) {
                int c2z = (ctmax & 3) + 1;  // zero dead half of last 32-chunk
                int u = 2 * c2z + (quad >> 1);
                *(bf16x4*)((char*)pb + l15 * 128 + ((u ^ l7) * 16)
                           + (quad & 1) * 8) =
                    (bf16x4){(bf16)0.f, (bf16)0.f, (bf16)0.f, (bf16)0.f};
            }
            asm volatile("" ::: "memory");  // keep ds_reads after ds_writes

            // PV for this quarter (ks2 = qp4*2 .. +1)
            #pragma unroll
            for (int k2 = 0; k2 < 2; ++k2) {
                int ks2 = qp4 * 2 + k2;
                if (ks2 <= (ctmax >> 1)) {  // wave-uniform
                    int ur = 4 * k2 + quad;
                    bf16x8 pf = *(const bf16x8*)((char*)pb + l15 * 128
                                                 + ((ur ^ l7) * 16));
                    #pragma unroll
                    for (int ht = 0; ht < 4; ++ht) {
                        int vr = ht * 16 + l15;
                        bf16x8 vf = *(const bf16x8*)((const char*)vs + vr * 512
                                     + (((ks2 * 4 + quad) ^ (vr & 31)) * 16));
                        o[ht] = MFMA16(vf, pf, o[ht]);
                    }
                }
            }
            asm volatile("" ::: "memory");  // pbuf reuse next quarter
        }
    }
    sm += __shfl_xor(sm, 16);
    sm += __shfl_xor(sm, 32);

    // Epilogue: normalize + packed fp32 stores (O^T: col=l15=qrow)
    float rinv = 1.0f / sm;
    #pragma unroll
    for (int ht = 0; ht < 4; ++ht) {
        f32x4 ov;
        #pragma unroll
        for (int r = 0; r < 4; ++r) ov[r] = o[ht][r] * rinv;
        *(f32x4*)(&out[((size_t)b * TT + t) * HH + ht * 16 + quad * 4]) = ov;
    }
}

// ---------------------------------------------------------------------------
extern "C" void kernel_launch(void* const* d_in, const int* in_sizes, int n_in,
                              void* d_out, int out_size, void* d_ws, size_t ws_size,
                              hipStream_t stream) {
    const float* x  = (const float*)d_in[0];
    const float* Wk = (const float*)d_in[1];
    const float* Wq = (const float*)d_in[2];
    const float* Wv = (const float*)d_in[3];

    bf16* wt = (bf16*)d_ws;                          // 3 * 512*64 elems
    float* out = (float*)d_out;

    wtrans<<<dim3(32, 3), 256, 0, stream>>>(Wk, Wq, Wv, wt);
    fused<<<dim3(256), 1024, 0, stream>>>(x, wt, out);
}